// Round 2
// baseline (102.857 us; speedup 1.0000x reference)
//
#include <hip/hip_runtime.h>
#include <hip/hip_bf16.h>
#include <cstdint>

#define BM 32
#define NTHREADS 320
#define WS_TILE 524288            // 64 u-steps * 8192 B per weight tensor (bf16 64x64)

typedef __bf16 bf16x8_t __attribute__((ext_vector_type(8)));
typedef float f32x4_t __attribute__((ext_vector_type(4)));

// Prep: fold scales, combine w011 + w101^T(u,v), store FRAGMENT-MAJOR per u-step:
//   ws[tile] + u*8192 + f*1024 + lane*16,  f = n*2+kf
// element (lane, j): w = 16n + (lane&15), v = 8*(lane>>4) + 32*kf + j
// -> each B-fragment load is one fully-coalesced 1KB wave read.
__global__ __launch_bounds__(256) void prep_weights(const float* __restrict__ w000,
                                                    const float* __restrict__ w110,
                                                    const float* __restrict__ w011,
                                                    const float* __restrict__ w101,
                                                    char* __restrict__ ws) {
  const float A0  = 0.011048543456039806f;   // sqrt(1/8192) ; also == ALPHA1/sqrt(3)
  const float A0I = A0 * 0.57735026918962576f;
  int t = blockIdx.x * 256 + threadIdx.x;    // 32768 threads: (u, f, lane)
  int u = t >> 9, f = (t >> 6) & 7, l = t & 63;
  int n = f >> 1, kf = f & 1;
  int w = 16 * n + (l & 15);
  int vbase = 8 * (l >> 4) + 32 * kf;
  bf16x8_t p0, p1, pc;
#pragma unroll
  for (int j = 0; j < 8; ++j) {
    int v = vbase + j;
    float a = w000[u * 4096 + v * 64 + w] * A0;
    float b = w110[u * 4096 + v * 64 + w] * A0I;
    float d = (w011[u * 4096 + v * 64 + w] + w101[v * 4096 + u * 64 + w]) * A0;
    p0[j] = (__bf16)a;
    p1[j] = (__bf16)b;
    pc[j] = (__bf16)d;
  }
  int off = u * 8192 + f * 1024 + l * 16;
  *(bf16x8_t*)(ws + off) = p0;
  *(bf16x8_t*)(ws + WS_TILE + off) = p1;
  *(bf16x8_t*)(ws + 2 * WS_TILE + off) = pc;
}

// Main: 256 blocks x 320 threads, BM=32 rows/block, 1 block/CU.
// wave 0: p000 ; wave 1: p110 (dot3 A) ; waves 2-4: out1 k = wave-2.
// B-fragments stream global->VGPR (L2/L1-resident), triple-buffered, NO loop barriers.
__global__ __launch_bounds__(NTHREADS, 1) void tp_main(const float* __restrict__ x,
                                                       const char* __restrict__ ws,
                                                       float* __restrict__ out) {
  __shared__ float xS[4 * 64 * 32];   // [vec][u][b] f32; reused as epilogue scratch
  const int tid = threadIdx.x;
  const int wave = tid >> 6, lane = tid & 63;
  const int lr = lane & 15, lg = lane >> 4;
  const int b0 = blockIdx.x * BM;
  const int role = wave;
  const int tsel = (role == 0) ? 0 : ((role == 1) ? 1 : 2);
  const bf16x8_t* wb = (const bf16x8_t*)(ws + tsel * WS_TILE) + lane;  // + u*512 + f*64

  // scalar table xS[vec][u][b]: vec0 = x0, vec 1+i = x1[:,:,i]
  for (int idx = tid; idx < 4 * 64 * 32; idx += NTHREADS) {
    int vec = idx >> 11, rem = idx & 2047;
    int uu = rem >> 5, bb = rem & 31;
    int col = (vec == 0) ? uu : (64 + 3 * uu + (vec - 1));
    xS[idx] = x[(b0 + bb) * 256 + col];
  }

  // per-wave x row-vector fragments in registers: xp[vi][m][kf][j] at
  // b = 16m + lr, v = 8*lg + 32*kf + j
  float xp[3][2][2][8];
  if (role == 1) {
#pragma unroll
    for (int vi = 0; vi < 3; ++vi)
#pragma unroll
      for (int m = 0; m < 2; ++m)
#pragma unroll
        for (int kf = 0; kf < 2; ++kf)
#pragma unroll
          for (int j = 0; j < 8; ++j) {
            int v = 8 * lg + 32 * kf + j;
            xp[vi][m][kf][j] = x[(b0 + 16 * m + lr) * 256 + 64 + 3 * v + vi];
          }
  } else {
    const int vsel = (role == 0) ? 0 : (role - 1);
#pragma unroll
    for (int m = 0; m < 2; ++m)
#pragma unroll
      for (int kf = 0; kf < 2; ++kf)
#pragma unroll
        for (int j = 0; j < 8; ++j) {
          int v = 8 * lg + 32 * kf + j;
          int col = (vsel == 0) ? v : (64 + 3 * v + (vsel - 1));
          xp[0][m][kf][j] = x[(b0 + 16 * m + lr) * 256 + col];
        }
  }

  f32x4_t acc[2][4];
#pragma unroll
  for (int m = 0; m < 2; ++m)
#pragma unroll
    for (int n = 0; n < 4; ++n) {
      f32x4_t z = {0.f, 0.f, 0.f, 0.f};
      acc[m][n] = z;
    }

  __syncthreads();   // xS visible to all waves; only barrier before epilogue

  auto LOADF = [&](bf16x8_t (&Bb)[8], int uu) {
#pragma unroll
    for (int f = 0; f < 8; ++f) Bb[f] = wb[uu * 512 + f * 64];
  };

  auto STEP = [&](bf16x8_t (&Bb)[8], int uu) {
    bf16x8_t afr[2][2];
    if (role == 1) {
      float s0a = xS[1 * 2048 + uu * 32 + lr],      s1a = xS[2 * 2048 + uu * 32 + lr],      s2a = xS[3 * 2048 + uu * 32 + lr];
      float s0b = xS[1 * 2048 + uu * 32 + 16 + lr], s1b = xS[2 * 2048 + uu * 32 + 16 + lr], s2b = xS[3 * 2048 + uu * 32 + 16 + lr];
#pragma unroll
      for (int kf = 0; kf < 2; ++kf)
#pragma unroll
        for (int j = 0; j < 8; ++j) {
          afr[0][kf][j] = (__bf16)(s0a * xp[0][0][kf][j] + s1a * xp[1][0][kf][j] + s2a * xp[2][0][kf][j]);
          afr[1][kf][j] = (__bf16)(s0b * xp[0][1][kf][j] + s1b * xp[1][1][kf][j] + s2b * xp[2][1][kf][j]);
        }
    } else {
      float sa = xS[uu * 32 + lr], sb = xS[uu * 32 + 16 + lr];
#pragma unroll
      for (int kf = 0; kf < 2; ++kf)
#pragma unroll
        for (int j = 0; j < 8; ++j) {
          afr[0][kf][j] = (__bf16)(sa * xp[0][0][kf][j]);
          afr[1][kf][j] = (__bf16)(sb * xp[0][1][kf][j]);
        }
    }
#pragma unroll
    for (int m = 0; m < 2; ++m)
#pragma unroll
      for (int n = 0; n < 4; ++n)
#pragma unroll
        for (int kf = 0; kf < 2; ++kf)
          acc[m][n] = __builtin_amdgcn_mfma_f32_16x16x32_bf16(afr[m][kf], Bb[n * 2 + kf], acc[m][n], 0, 0, 0);
  };

  // triple-buffered register pipeline, hand-rotated (all indices static)
  bf16x8_t B0[8], B1[8], B2[8];
  LOADF(B0, 0);
  LOADF(B1, 1);
  for (int u = 0; u < 60; u += 3) {   // bases 0,3,...,57
    LOADF(B2, u + 2);
    STEP(B0, u);
    LOADF(B0, u + 3);
    STEP(B1, u + 1);
    LOADF(B1, u + 4);
    STEP(B2, u + 2);
  }
  // base 60 tail: B0=60, B1=61 already resident
  LOADF(B2, 62);
  STEP(B0, 60);
  LOADF(B0, 63);
  STEP(B1, 61);
  STEP(B2, 62);
  STEP(B0, 63);

  // epilogue: out0 = p000 + p110 (cross-wave via LDS), out1 strided store
  __syncthreads();                 // all xS scalar reads complete
  float* pscr = xS;                // 32x64 f32 scratch (8 KB)
  if (role == 1) {
#pragma unroll
    for (int m = 0; m < 2; ++m)
#pragma unroll
      for (int n = 0; n < 4; ++n)
#pragma unroll
        for (int r = 0; r < 4; ++r)
          pscr[(16 * m + 4 * lg + r) * 64 + 16 * n + lr] = acc[m][n][r];
  }
  __syncthreads();
  if (role == 0) {
#pragma unroll
    for (int m = 0; m < 2; ++m)
#pragma unroll
      for (int n = 0; n < 4; ++n)
#pragma unroll
        for (int r = 0; r < 4; ++r) {
          int row = 16 * m + 4 * lg + r, col = 16 * n + lr;
          out[(b0 + row) * 256 + col] = acc[m][n][r] + pscr[row * 64 + col];
        }
  } else if (role >= 2) {
    const int k = role - 2;
#pragma unroll
    for (int m = 0; m < 2; ++m)
#pragma unroll
      for (int n = 0; n < 4; ++n)
#pragma unroll
        for (int r = 0; r < 4; ++r) {
          int row = 16 * m + 4 * lg + r, col = 16 * n + lr;
          out[(b0 + row) * 256 + 64 + 3 * col + k] = acc[m][n][r];
        }
  }
}

extern "C" void kernel_launch(void* const* d_in, const int* in_sizes, int n_in,
                              void* d_out, int out_size, void* d_ws, size_t ws_size,
                              hipStream_t stream) {
  const float* x    = (const float*)d_in[0];
  const float* w000 = (const float*)d_in[1];
  const float* w110 = (const float*)d_in[2];
  const float* w011 = (const float*)d_in[3];
  const float* w101 = (const float*)d_in[4];
  float* out = (float*)d_out;
  char* ws = (char*)d_ws;

  prep_weights<<<128, 256, 0, stream>>>(w000, w110, w011, w101, ws);
  tp_main<<<256, NTHREADS, 0, stream>>>(x, ws, out);
}

// Round 3
// 59.738 us; speedup vs baseline: 1.7218x; 1.7218x over previous
//
#include <hip/hip_runtime.h>
#include <hip/hip_bf16.h>
#include <cstdint>

#define BM 32
#define NTHREADS 320
#define WS_TILE 524288            // 64 u-steps * 8192 B per weight tensor (bf16 64x64)
#define BUF_B 24576               // one u-step buffer: 3 tensor tiles * 8192 B
#define SMEM_BYTES (3*BUF_B + 4*64*32*4)   // 73728 + 32768 = 106496

typedef __bf16 bf16x8_t __attribute__((ext_vector_type(8)));
typedef float f32x4_t __attribute__((ext_vector_type(4)));

__device__ __forceinline__ void async_ld16(const void* g, void* l) {
  __builtin_amdgcn_global_load_lds((const __attribute__((address_space(1))) unsigned int*)g,
                                   (__attribute__((address_space(3))) unsigned int*)l,
                                   16, 0, 0);
}

// counted-vmcnt barrier: never drain the in-flight prefetch (T3/T4).
// 8 loads/step/wave in flight for u+2 stay outstanding; waits for u+1's 8.
#define SYNC_V8() asm volatile("s_waitcnt vmcnt(8) lgkmcnt(0)\n\ts_barrier" ::: "memory")
#define SYNC_V0() asm volatile("s_waitcnt vmcnt(0) lgkmcnt(0)\n\ts_barrier" ::: "memory")

// Prep: fold scales, combine w011 + w101^T(u,v), store FRAGMENT-MAJOR per u-step:
//   ws[tile] + u*8192 + f*1024 + lane*16,  f = n*2+kf
// element (lane, j): w = 16n + (lane&15), v = 8*(lane>>4) + 32*kf + j
// -> staging is linear 1KB wave-bursts AND LDS fragment reads are linear
//    lane*16 bursts: conflict-free on both sides, no swizzle anywhere.
__global__ __launch_bounds__(256) void prep_weights(const float* __restrict__ w000,
                                                    const float* __restrict__ w110,
                                                    const float* __restrict__ w011,
                                                    const float* __restrict__ w101,
                                                    char* __restrict__ ws) {
  const float A0  = 0.011048543456039806f;   // sqrt(1/8192) ; also == ALPHA1/sqrt(3)
  const float A0I = A0 * 0.57735026918962576f;
  int t = blockIdx.x * 256 + threadIdx.x;    // 32768 threads: (u, f, lane)
  int u = t >> 9, f = (t >> 6) & 7, l = t & 63;
  int n = f >> 1, kf = f & 1;
  int w = 16 * n + (l & 15);
  int vbase = 8 * (l >> 4) + 32 * kf;
  bf16x8_t p0, p1, pc;
#pragma unroll
  for (int j = 0; j < 8; ++j) {
    int v = vbase + j;
    float a = w000[u * 4096 + v * 64 + w] * A0;
    float b = w110[u * 4096 + v * 64 + w] * A0I;
    float d = (w011[u * 4096 + v * 64 + w] + w101[v * 4096 + u * 64 + w]) * A0;
    p0[j] = (__bf16)a;
    p1[j] = (__bf16)b;
    pc[j] = (__bf16)d;
  }
  int off = u * 8192 + f * 1024 + l * 16;
  *(bf16x8_t*)(ws + off) = p0;
  *(bf16x8_t*)(ws + WS_TILE + off) = p1;
  *(bf16x8_t*)(ws + 2 * WS_TILE + off) = pc;
}

// Main: 256 blocks x 320 threads, BM=32 rows/block, 1 block/CU.
// wave 0: p000 ; wave 1: p110 (dot3 A) ; waves 2-4: out1 k = wave-2.
// 3 LDS u-buffers, depth-2 prefetch via global_load_lds, raw barriers with
// counted vmcnt(8) so the prefetch queue is never drained.
__global__ __launch_bounds__(NTHREADS, 1) void tp_main(const float* __restrict__ x,
                                                       const char* __restrict__ ws,
                                                       float* __restrict__ out) {
  extern __shared__ char smem[];
  float* xS = (float*)(smem + 3 * BUF_B);   // [vec][u][b] f32, 4*64*32
  const int tid = threadIdx.x;
  const int wave = tid >> 6, lane = tid & 63;
  const int lr = lane & 15, lg = lane >> 4;
  const int b0 = blockIdx.x * BM;
  const int role = wave;
  const int tsel = (role == 0) ? 0 : ((role == 1) ? 1 : 2);

  // stage tile for u-step `uu` of this wave's tensor into buffer at byte `bufB`
  auto STAGE = [&](int uu, int bufB) {
    if (wave < 3) {
      const char* g = ws + wave * WS_TILE + uu * 8192 + lane * 16;
      char* l = smem + bufB + wave * 8192;
#pragma unroll
      for (int c = 0; c < 8; ++c)
        async_ld16(g + c * 1024, l + c * 1024);
    }
  };

  auto LOADB = [&](bf16x8_t (&bfr)[8], int bufB) {
    const char* wt = smem + bufB + tsel * 8192 + lane * 16;
#pragma unroll
    for (int f = 0; f < 8; ++f)
      bfr[f] = *(const bf16x8_t*)(wt + f * 1024);
  };

  // prologue: stage u=0 -> buf0, u=1 -> buf1
  STAGE(0, 0);
  STAGE(1, BUF_B);

  // scalar table xS[vec][u][b]: vec0 = x0, vec 1+i = x1[:,:,i]
  for (int idx = tid; idx < 4 * 64 * 32; idx += NTHREADS) {
    int vec = idx >> 11, rem = idx & 2047;
    int uu = rem >> 5, bb = rem & 31;
    int col = (vec == 0) ? uu : (64 + 3 * uu + (vec - 1));
    xS[idx] = x[(b0 + bb) * 256 + col];
  }

  // per-wave x row-vector fragments in registers: xp[vi][m][kf][j] at
  // b = 16m + lr, v = 8*lg + 32*kf + j
  float xp[3][2][2][8];
  if (role == 1) {
#pragma unroll
    for (int vi = 0; vi < 3; ++vi)
#pragma unroll
      for (int m = 0; m < 2; ++m)
#pragma unroll
        for (int kf = 0; kf < 2; ++kf)
#pragma unroll
          for (int j = 0; j < 8; ++j) {
            int v = 8 * lg + 32 * kf + j;
            xp[vi][m][kf][j] = x[(b0 + 16 * m + lr) * 256 + 64 + 3 * v + vi];
          }
  } else {
    const int vsel = (role == 0) ? 0 : (role - 1);
#pragma unroll
    for (int m = 0; m < 2; ++m)
#pragma unroll
      for (int kf = 0; kf < 2; ++kf)
#pragma unroll
        for (int j = 0; j < 8; ++j) {
          int v = 8 * lg + 32 * kf + j;
          int col = (vsel == 0) ? v : (64 + 3 * v + (vsel - 1));
          xp[0][m][kf][j] = x[(b0 + 16 * m + lr) * 256 + col];
        }
  }

  f32x4_t acc[2][4];
#pragma unroll
  for (int m = 0; m < 2; ++m)
#pragma unroll
    for (int n = 0; n < 4; ++n) {
      f32x4_t z = {0.f, 0.f, 0.f, 0.f};
      acc[m][n] = z;
    }

  auto STEP = [&](bf16x8_t (&bfr)[8], int uu) {
    bf16x8_t afr[2][2];
    if (role == 1) {
      float s0a = xS[1 * 2048 + uu * 32 + lr],      s1a = xS[2 * 2048 + uu * 32 + lr],      s2a = xS[3 * 2048 + uu * 32 + lr];
      float s0b = xS[1 * 2048 + uu * 32 + 16 + lr], s1b = xS[2 * 2048 + uu * 32 + 16 + lr], s2b = xS[3 * 2048 + uu * 32 + 16 + lr];
#pragma unroll
      for (int kf = 0; kf < 2; ++kf)
#pragma unroll
        for (int j = 0; j < 8; ++j) {
          afr[0][kf][j] = (__bf16)(s0a * xp[0][0][kf][j] + s1a * xp[1][0][kf][j] + s2a * xp[2][0][kf][j]);
          afr[1][kf][j] = (__bf16)(s0b * xp[0][1][kf][j] + s1b * xp[1][1][kf][j] + s2b * xp[2][1][kf][j]);
        }
    } else {
      float sa = xS[uu * 32 + lr], sb = xS[uu * 32 + 16 + lr];
#pragma unroll
      for (int kf = 0; kf < 2; ++kf)
#pragma unroll
        for (int j = 0; j < 8; ++j) {
          afr[0][kf][j] = (__bf16)(sa * xp[0][0][kf][j]);
          afr[1][kf][j] = (__bf16)(sb * xp[0][1][kf][j]);
        }
    }
#pragma unroll
    for (int m = 0; m < 2; ++m)
#pragma unroll
      for (int n = 0; n < 4; ++n)
#pragma unroll
        for (int kf = 0; kf < 2; ++kf)
          acc[m][n] = __builtin_amdgcn_mfma_f32_16x16x32_bf16(afr[m][kf], bfr[n * 2 + kf], acc[m][n], 0, 0, 0);
  };

  // tile0 ready (16 staging loads out, keep newest 8), xS visible
  SYNC_V8();

  bf16x8_t bfr[8];
  // main loop: u = base..base+2, buffer index = u % 3 (static per position)
  for (int base = 0; base < 60; base += 3) {
    STAGE(base + 2, 2 * BUF_B);
    LOADB(bfr, 0);
    STEP(bfr, base);
    SYNC_V8();

    STAGE(base + 3, 0);
    LOADB(bfr, BUF_B);
    STEP(bfr, base + 1);
    SYNC_V8();

    STAGE(base + 4, BUF_B);
    LOADB(bfr, 2 * BUF_B);
    STEP(bfr, base + 2);
    SYNC_V8();
  }
  // tail: u = 60..63
  STAGE(62, 2 * BUF_B);
  LOADB(bfr, 0);
  STEP(bfr, 60);
  SYNC_V8();

  STAGE(63, 0);
  LOADB(bfr, BUF_B);
  STEP(bfr, 61);
  SYNC_V8();

  LOADB(bfr, 2 * BUF_B);
  STEP(bfr, 62);
  SYNC_V0();

  LOADB(bfr, 0);
  STEP(bfr, 63);

  // epilogue: out0 = p000 + p110 (cross-wave via LDS), out1 strided store
  __syncthreads();                 // all loop LDS reads complete everywhere
  float* pscr = (float*)smem;      // 32x64 f32 scratch (8 KB), tiles dead now
  if (role == 1) {
#pragma unroll
    for (int m = 0; m < 2; ++m)
#pragma unroll
      for (int n = 0; n < 4; ++n)
#pragma unroll
        for (int r = 0; r < 4; ++r)
          pscr[(16 * m + 4 * lg + r) * 64 + 16 * n + lr] = acc[m][n][r];
  }
  __syncthreads();
  if (role == 0) {
#pragma unroll
    for (int m = 0; m < 2; ++m)
#pragma unroll
      for (int n = 0; n < 4; ++n)
#pragma unroll
        for (int r = 0; r < 4; ++r) {
          int row = 16 * m + 4 * lg + r, col = 16 * n + lr;
          out[(b0 + row) * 256 + col] = acc[m][n][r] + pscr[row * 64 + col];
        }
  } else if (role >= 2) {
    const int k = role - 2;
#pragma unroll
    for (int m = 0; m < 2; ++m)
#pragma unroll
      for (int n = 0; n < 4; ++n)
#pragma unroll
        for (int r = 0; r < 4; ++r) {
          int row = 16 * m + 4 * lg + r, col = 16 * n + lr;
          out[(b0 + row) * 256 + 64 + 3 * col + k] = acc[m][n][r];
        }
  }
}

extern "C" void kernel_launch(void* const* d_in, const int* in_sizes, int n_in,
                              void* d_out, int out_size, void* d_ws, size_t ws_size,
                              hipStream_t stream) {
  const float* x    = (const float*)d_in[0];
  const float* w000 = (const float*)d_in[1];
  const float* w110 = (const float*)d_in[2];
  const float* w011 = (const float*)d_in[3];
  const float* w101 = (const float*)d_in[4];
  float* out = (float*)d_out;
  char* ws = (char*)d_ws;

  prep_weights<<<128, 256, 0, stream>>>(w000, w110, w011, w101, ws);

  hipFuncSetAttribute((const void*)tp_main, hipFuncAttributeMaxDynamicSharedMemorySize, SMEM_BYTES);
  tp_main<<<256, NTHREADS, SMEM_BYTES, stream>>>(x, ws, out);
}

// Round 4
// 49.750 us; speedup vs baseline: 2.0675x; 1.2008x over previous
//
#include <hip/hip_runtime.h>
#include <hip/hip_bf16.h>
#include <cstdint>

#define BM 32
#define NTHREADS 640              // 10 waves
#define WS_TILE 524288            // 64 u-steps * 8192 B per weight tensor (bf16 64x64)
#define BUF_B 24576               // one u-step buffer: 3 tensor tiles * 8192 B
#define SMEM_BYTES (3*BUF_B + 4*64*32*4)   // 73728 + 32768 = 106496

typedef __bf16 bf16x8_t __attribute__((ext_vector_type(8)));
typedef float f32x4_t __attribute__((ext_vector_type(4)));

__device__ __forceinline__ void async_ld16(const void* g, void* l) {
  __builtin_amdgcn_global_load_lds((const __attribute__((address_space(1))) unsigned int*)g,
                                   (__attribute__((address_space(3))) unsigned int*)l,
                                   16, 0, 0);
}

// counted-vmcnt barrier: each staging wave keeps its 4 next-next-step loads
// in flight across the barrier; waits only for the next-step tile.
#define SYNC_V4() asm volatile("s_waitcnt vmcnt(4) lgkmcnt(0)\n\ts_barrier" ::: "memory")
#define SYNC_V0() asm volatile("s_waitcnt vmcnt(0) lgkmcnt(0)\n\ts_barrier" ::: "memory")

// Prep: fold scales, combine w011 + w101^T(u,v), store FRAGMENT-MAJOR per u-step:
//   ws[tile] + u*8192 + f*1024 + lane*16,  f = n*2+kf
// element (lane, j): w = 16n + (lane&15), v = 8*(lane>>4) + 32*kf + j
__global__ __launch_bounds__(256) void prep_weights(const float* __restrict__ w000,
                                                    const float* __restrict__ w110,
                                                    const float* __restrict__ w011,
                                                    const float* __restrict__ w101,
                                                    char* __restrict__ ws) {
  const float A0  = 0.011048543456039806f;   // sqrt(1/8192) ; also == ALPHA1/sqrt(3)
  const float A0I = A0 * 0.57735026918962576f;
  int t = blockIdx.x * 256 + threadIdx.x;    // 32768 threads: (u, f, lane)
  int u = t >> 9, f = (t >> 6) & 7, l = t & 63;
  int n = f >> 1, kf = f & 1;
  int w = 16 * n + (l & 15);
  int vbase = 8 * (l >> 4) + 32 * kf;
  bf16x8_t p0, p1, pc;
#pragma unroll
  for (int j = 0; j < 8; ++j) {
    int v = vbase + j;
    float a = w000[u * 4096 + v * 64 + w] * A0;
    float b = w110[u * 4096 + v * 64 + w] * A0I;
    float d = (w011[u * 4096 + v * 64 + w] + w101[v * 4096 + u * 64 + w]) * A0;
    p0[j] = (__bf16)a;
    p1[j] = (__bf16)b;
    pc[j] = (__bf16)d;
  }
  int off = u * 8192 + f * 1024 + l * 16;
  *(bf16x8_t*)(ws + off) = p0;
  *(bf16x8_t*)(ws + WS_TILE + off) = p1;
  *(bf16x8_t*)(ws + 2 * WS_TILE + off) = pc;
}

// Main: 256 blocks x 640 threads (10 waves), BM=32 rows/block, 1 block/CU.
// wave = 2*unit + kf.  unit 0: p000 ; unit 1: p110 (dot3 A) ; units 2-4: out1 k=unit-2.
// Each wave handles ONE K-half (kf) of its unit: 4 B-frags, 8 MFMA, half A-build.
// kf-pairs sum their accumulators in the epilogue via LDS.
__global__ __launch_bounds__(NTHREADS, 1) void tp_main(const float* __restrict__ x,
                                                       const char* __restrict__ ws,
                                                       float* __restrict__ out) {
  extern __shared__ char smem[];
  float* xS = (float*)(smem + 3 * BUF_B);   // [vec][u][b] f32, 4*64*32
  const int tid = threadIdx.x;
  const int wave = tid >> 6, lane = tid & 63;
  const int lr = lane & 15, lg = lane >> 4;
  const int b0 = blockIdx.x * BM;
  const int unit = wave >> 1;               // 0..4
  const int kf = wave & 1;
  const int tsel = (unit == 0) ? 0 : ((unit == 1) ? 1 : 2);

  // stage: waves 0-5 each stage one half-tile (4KB = 4 chunks) per step.
  // wave w covers tensor (w>>1), half (w&1).
  auto STAGE = [&](int uu, int bufB) {
    if (wave < 6) {
      const char* g = ws + (wave >> 1) * WS_TILE + uu * 8192 + (wave & 1) * 4096 + lane * 16;
      char* l = smem + bufB + (wave >> 1) * 8192 + (wave & 1) * 4096 + lane * 16;
#pragma unroll
      for (int c = 0; c < 4; ++c)
        async_ld16(g + c * 1024, l + c * 1024);
    }
  };

  // 4 B-frags for this wave's kf: frag index f = 2n + kf
  auto LOADB = [&](bf16x8_t (&bfr)[4], int bufB) {
    const char* wt = smem + bufB + tsel * 8192 + kf * 1024 + lane * 16;
#pragma unroll
    for (int n = 0; n < 4; ++n)
      bfr[n] = *(const bf16x8_t*)(wt + n * 2048);
  };

  // prologue: stage u=0 -> buf0, u=1 -> buf1
  STAGE(0, 0);
  STAGE(1, BUF_B);

  // scalar table xS[vec][u][b]: vec0 = x0, vec 1+i = x1[:,:,i]
  for (int idx = tid; idx < 4 * 64 * 32; idx += NTHREADS) {
    int vec = idx >> 11, rem = idx & 2047;
    int uu = rem >> 5, bb = rem & 31;
    int col = (vec == 0) ? uu : (64 + 3 * uu + (vec - 1));
    xS[idx] = x[(b0 + bb) * 256 + col];
  }

  // per-wave x row-vectors (only this wave's kf half): v = 8*lg + 32*kf + j
  float xp[3][2][8];    // [vi][m][j]; units != 1 use vi=0 only
  if (unit == 1) {
#pragma unroll
    for (int vi = 0; vi < 3; ++vi)
#pragma unroll
      for (int m = 0; m < 2; ++m)
#pragma unroll
        for (int j = 0; j < 8; ++j) {
          int v = 8 * lg + 32 * kf + j;
          xp[vi][m][j] = x[(b0 + 16 * m + lr) * 256 + 64 + 3 * v + vi];
        }
  } else {
#pragma unroll
    for (int m = 0; m < 2; ++m)
#pragma unroll
      for (int j = 0; j < 8; ++j) {
        int v = 8 * lg + 32 * kf + j;
        int col = (unit == 0) ? v : (64 + 3 * v + (unit - 2));
        xp[0][m][j] = x[(b0 + 16 * m + lr) * 256 + col];
      }
  }

  f32x4_t acc[2][4];
#pragma unroll
  for (int m = 0; m < 2; ++m)
#pragma unroll
    for (int n = 0; n < 4; ++n) {
      f32x4_t z = {0.f, 0.f, 0.f, 0.f};
      acc[m][n] = z;
    }

  auto STEP = [&](bf16x8_t (&bfr)[4], int uu) {
    bf16x8_t afr[2];
    if (unit == 1) {
#pragma unroll
      for (int m = 0; m < 2; ++m) {
        float s0 = xS[1 * 2048 + uu * 32 + 16 * m + lr];
        float s1 = xS[2 * 2048 + uu * 32 + 16 * m + lr];
        float s2 = xS[3 * 2048 + uu * 32 + 16 * m + lr];
#pragma unroll
        for (int j = 0; j < 8; ++j)
          afr[m][j] = (__bf16)(s0 * xp[0][m][j] + s1 * xp[1][m][j] + s2 * xp[2][m][j]);
      }
    } else {
#pragma unroll
      for (int m = 0; m < 2; ++m) {
        float s = xS[uu * 32 + 16 * m + lr];
#pragma unroll
        for (int j = 0; j < 8; ++j)
          afr[m][j] = (__bf16)(s * xp[0][m][j]);
      }
    }
#pragma unroll
    for (int m = 0; m < 2; ++m)
#pragma unroll
      for (int n = 0; n < 4; ++n)
        acc[m][n] = __builtin_amdgcn_mfma_f32_16x16x32_bf16(afr[m], bfr[n], acc[m][n], 0, 0, 0);
  };

  // tile0 ready (8 staging loads out per staging wave, keep newest 4), xS visible
  SYNC_V4();

  bf16x8_t bfr[4];
  for (int base = 0; base < 60; base += 3) {
    STAGE(base + 2, 2 * BUF_B);
    LOADB(bfr, 0);
    STEP(bfr, base);
    SYNC_V4();

    STAGE(base + 3, 0);
    LOADB(bfr, BUF_B);
    STEP(bfr, base + 1);
    SYNC_V4();

    STAGE(base + 4, BUF_B);
    LOADB(bfr, 2 * BUF_B);
    STEP(bfr, base + 2);
    SYNC_V4();
  }
  // tail: u = 60..63
  STAGE(62, 2 * BUF_B);
  LOADB(bfr, 0);
  STEP(bfr, 60);
  SYNC_V4();

  STAGE(63, 0);
  LOADB(bfr, BUF_B);
  STEP(bfr, 61);
  SYNC_V4();

  LOADB(bfr, 2 * BUF_B);
  STEP(bfr, 62);
  SYNC_V0();

  LOADB(bfr, 0);
  STEP(bfr, 63);

  // ---- epilogue ----
  __syncthreads();                  // all loop LDS reads complete; tiles dead
  float* pscr = (float*)smem;       // [6][32][64] f32 = 48KB scratch in tile area
  // phase 1: kf=1 waves dump acc
  if (kf == 1) {
#pragma unroll
    for (int m = 0; m < 2; ++m)
#pragma unroll
      for (int n = 0; n < 4; ++n)
#pragma unroll
        for (int r = 0; r < 4; ++r)
          pscr[unit * 2048 + (16 * m + 4 * lg + r) * 64 + 16 * n + lr] = acc[m][n][r];
  }
  __syncthreads();
  // phase 2: kf=0 waves fold in their pair's half; wave 2 (p110) republishes sum
  if (kf == 0) {
#pragma unroll
    for (int m = 0; m < 2; ++m)
#pragma unroll
      for (int n = 0; n < 4; ++n)
#pragma unroll
        for (int r = 0; r < 4; ++r)
          acc[m][n][r] += pscr[unit * 2048 + (16 * m + 4 * lg + r) * 64 + 16 * n + lr];
    if (unit == 1) {
#pragma unroll
      for (int m = 0; m < 2; ++m)
#pragma unroll
        for (int n = 0; n < 4; ++n)
#pragma unroll
          for (int r = 0; r < 4; ++r)
            pscr[5 * 2048 + (16 * m + 4 * lg + r) * 64 + 16 * n + lr] = acc[m][n][r];
    }
  }
  __syncthreads();
  // phase 3: stores
  if (wave == 0) {                  // out0 = p000 + p110
#pragma unroll
    for (int m = 0; m < 2; ++m)
#pragma unroll
      for (int n = 0; n < 4; ++n)
#pragma unroll
        for (int r = 0; r < 4; ++r) {
          int row = 16 * m + 4 * lg + r, col = 16 * n + lr;
          out[(b0 + row) * 256 + col] = acc[m][n][r] + pscr[5 * 2048 + row * 64 + col];
        }
  } else if (kf == 0 && unit >= 2) {  // out1, k = unit-2
    const int k = unit - 2;
#pragma unroll
    for (int m = 0; m < 2; ++m)
#pragma unroll
      for (int n = 0; n < 4; ++n)
#pragma unroll
        for (int r = 0; r < 4; ++r) {
          int row = 16 * m + 4 * lg + r, col = 16 * n + lr;
          out[(b0 + row) * 256 + 64 + 3 * col + k] = acc[m][n][r];
        }
  }
}

extern "C" void kernel_launch(void* const* d_in, const int* in_sizes, int n_in,
                              void* d_out, int out_size, void* d_ws, size_t ws_size,
                              hipStream_t stream) {
  const float* x    = (const float*)d_in[0];
  const float* w000 = (const float*)d_in[1];
  const float* w110 = (const float*)d_in[2];
  const float* w011 = (const float*)d_in[3];
  const float* w101 = (const float*)d_in[4];
  float* out = (float*)d_out;
  char* ws = (char*)d_ws;

  prep_weights<<<128, 256, 0, stream>>>(w000, w110, w011, w101, ws);

  hipFuncSetAttribute((const void*)tp_main, hipFuncAttributeMaxDynamicSharedMemorySize, SMEM_BYTES);
  tp_main<<<256, NTHREADS, SMEM_BYTES, stream>>>(x, ws, out);
}